// Round 3
// baseline (87.178 us; speedup 1.0000x reference)
//
#include <hip/hip_runtime.h>
#include <math.h>

#define HH 256
#define WW 256
#define HWSZ (HH * WW)
#define KE 4096
#define NSLICE 16

#define QPB 1024              // queries per block (4 per thread)
#define TPB 512               // targets per block chunk
#define NQB (KE / QPB)        // 4
#define NTB (KE / TPB)        // 8
#define SENT 0x7f7f7f7fu      // large-float sentinel (3.39e38), > any real d2

typedef unsigned long long u64;

// ---------------------------------------------------------------------------
// Kernel 1: binarize + bit-pack (and init the part[] min-array to sentinel).
// One block per image row (2 x 16 x 256 = 8192 blocks). Lane thresholds one
// pixel; ballot packs 64 cols -> u64. bm layout: [tensor][slice][row][word4].
// Blocks 0..511 additionally init part[] (32 x 4096 uints = 512 x 256).
// ---------------------------------------------------------------------------
__global__ void __launch_bounds__(256) binarize_pack(
        const float* __restrict__ gth, const float* __restrict__ pred,
        u64* __restrict__ bm, unsigned* __restrict__ part) {
    int b = blockIdx.x;                 // tensor*4096 + slice*256 + row
    if (b < 512) part[b * 256 + threadIdx.x] = SENT;
    int tensor = b >> 12;
    int sr = b & 4095;
    const float* img = tensor ? pred : gth;
    float v = img[sr * WW + threadIdx.x];
    u64 bal = __ballot(v > 0.5f);
    int lane = threadIdx.x & 63;
    int wave = threadIdx.x >> 6;
    if (lane == 0) bm[(size_t)b * 4 + wave] = bal;
}

// ---------------------------------------------------------------------------
// Kernel 2: bitwise edge detect + ordered compaction (unchanged from r2).
// 32 blocks (tensor, slice), thread = row. Erosion with +inf padding:
//   vert  = rowAbove & row & rowBelow      (OOB row = all-ones)
//   erode = vert & shl1 & shr1             (OOB col carry-in = 1)
//   edge  = row & ~erode
// Row popcounts -> block scan -> ordered writes (matches jnp.nonzero order).
// Truncate at KE, store FULL count (divisor).
// ---------------------------------------------------------------------------
__global__ void __launch_bounds__(256) edge_compact2(
        const u64* __restrict__ bm,
        float2* __restrict__ gpts, float2* __restrict__ ppts,
        int* __restrict__ gcnt, int* __restrict__ pcnt) {
    int b = blockIdx.x;                 // 0..31
    int tensor = b >> 4;
    int slice = b & 15;
    const u64* rm = bm + (size_t)(tensor * 4096 + slice * 256) * 4;
    float2* pts = (tensor ? ppts : gpts) + slice * KE;
    int* cnt = (tensor ? pcnt : gcnt) + slice;

    int row = threadIdx.x;
    u64 vc[4], va[4], vb[4];
#pragma unroll
    for (int w = 0; w < 4; ++w) {
        vc[w] = rm[row * 4 + w];
        va[w] = (row > 0) ? rm[(row - 1) * 4 + w] : ~0ull;
        vb[w] = (row < HH - 1) ? rm[(row + 1) * 4 + w] : ~0ull;
    }
    u64 vert[4];
#pragma unroll
    for (int w = 0; w < 4; ++w) vert[w] = va[w] & vc[w] & vb[w];
    u64 e[4];
#pragma unroll
    for (int w = 0; w < 4; ++w) {
        u64 left  = (vert[w] << 1) | ((w > 0) ? (vert[w - 1] >> 63) : 1ull);
        u64 right = (vert[w] >> 1) | (((w < 3) ? (vert[w + 1] & 1ull) : 1ull) << 63);
        e[w] = vc[w] & ~(vert[w] & left & right);
    }
    int mycnt = __popcll(e[0]) + __popcll(e[1]) + __popcll(e[2]) + __popcll(e[3]);

    __shared__ int sc[256];
    sc[row] = mycnt;
    __syncthreads();
    for (int d = 1; d < 256; d <<= 1) {
        int v = (row >= d) ? sc[row - d] : 0;
        __syncthreads();
        sc[row] += v;
        __syncthreads();
    }
    int off = sc[row] - mycnt;          // exclusive prefix
#pragma unroll
    for (int w = 0; w < 4; ++w) {
        u64 bits = e[w];
        while (bits) {
            int l = __ffsll((long long)bits) - 1;
            bits &= bits - 1;
            if (off < KE) pts[off] = make_float2((float)row, (float)(w * 64 + l));
            ++off;
        }
    }
    if (row == HH - 1) *cnt = sc[HH - 1];
}

// ---------------------------------------------------------------------------
// Kernel 3: partial nearest-neighbor minima. Grid = slice x dir x qblk x tblk
// = 16*2*4*8 = 1024 blocks. Each thread owns 4 queries (independent min
// chains, LDS reads amortized 4x); each block covers a 512-target chunk in
// 4 KB of LDS. Results merged via atomicMin on uint-reinterpreted floats
// (non-negative => bit order == numeric order; commutative => deterministic).
// ---------------------------------------------------------------------------
__global__ void __launch_bounds__(256) mindist_part(
        const float2* __restrict__ gpts, const float2* __restrict__ ppts,
        const int* __restrict__ gcnt, const int* __restrict__ pcnt,
        unsigned* __restrict__ part) {
    int b = blockIdx.x;
    int tb = b & (NTB - 1);
    int qb = (b >> 3) & (NQB - 1);
    int dir = (b >> 5) & 1;             // 0: g->p, 1: p->g
    int slice = b >> 6;

    int qfull = dir ? pcnt[slice] : gcnt[slice];
    int tfull = dir ? gcnt[slice] : pcnt[slice];
    int qc = min(qfull, KE);
    int tc = min(tfull, KE);
    if (qb * QPB >= qc || tb * TPB >= tc) return;

    const float2* q = (dir ? ppts : gpts) + slice * KE;
    const float2* t = (dir ? gpts : ppts) + slice * KE;
    unsigned* prow = part + (size_t)(slice * 2 + dir) * KE;

    __shared__ float2 tp[TPB];
    int t0 = tb * TPB;
    int tn = min(tc - t0, TPB);
    int tnp = (tn + 3) & ~3;
    int tid = threadIdx.x;
    for (int i = tid; i < tnp; i += 256)
        tp[i] = (i < tn) ? t[t0 + i] : make_float2(1e9f, 1e9f);
    __syncthreads();

    int qi[4];
    float2 qp[4];
    float m[4];
#pragma unroll
    for (int k = 0; k < 4; ++k) {
        qi[k] = qb * QPB + k * 256 + tid;
        qp[k] = q[min(qi[k], qc - 1)];  // clamp; invalid lanes never written
        m[k] = INFINITY;
    }
    for (int j = 0; j < tnp; j += 4) {
        float2 a0 = tp[j], a1 = tp[j + 1], a2 = tp[j + 2], a3 = tp[j + 3];
#pragma unroll
        for (int k = 0; k < 4; ++k) {
            float dy0 = qp[k].x - a0.x, dx0 = qp[k].y - a0.y;
            float dy1 = qp[k].x - a1.x, dx1 = qp[k].y - a1.y;
            float dy2 = qp[k].x - a2.x, dx2 = qp[k].y - a2.y;
            float dy3 = qp[k].x - a3.x, dx3 = qp[k].y - a3.y;
            float d0 = dy0 * dy0 + dx0 * dx0;
            float d1 = dy1 * dy1 + dx1 * dx1;
            float d2 = dy2 * dy2 + dx2 * dx2;
            float d3 = dy3 * dy3 + dx3 * dx3;
            m[k] = fminf(m[k], fminf(fminf(d0, d1), fminf(d2, d3)));
        }
    }
#pragma unroll
    for (int k = 0; k < 4; ++k)
        if (qi[k] < qc)
            atomicMin(&prow[qi[k]], __float_as_uint(m[k]));
}

// ---------------------------------------------------------------------------
// Kernel 4: per-(slice,dir) fold: min -> sqrt -> sum. 32 blocks x 256.
// ---------------------------------------------------------------------------
__global__ void __launch_bounds__(256) combine(
        const int* __restrict__ gcnt, const int* __restrict__ pcnt,
        const unsigned* __restrict__ part,
        float* __restrict__ gsum, float* __restrict__ psum) {
    int sd = blockIdx.x;                // slice*2 + dir
    int slice = sd >> 1;
    int dir = sd & 1;
    int qc = min(dir ? pcnt[slice] : gcnt[slice], KE);
    const unsigned* prow = part + (size_t)sd * KE;
    int tid = threadIdx.x;

    float val = 0.0f;
    for (int qi = tid; qi < qc; qi += 256)
        val += sqrtf(__uint_as_float(prow[qi]));

    __shared__ float red[256];
    red[tid] = val;
    __syncthreads();
    for (int s = 128; s > 0; s >>= 1) {
        if (tid < s) red[tid] += red[tid + s];
        __syncthreads();
    }
    if (tid == 0) (dir ? psum : gsum)[slice] = red[0];
}

// ---------------------------------------------------------------------------
// Kernel 5: per-slice ahd -> loss -> nanmean. Slice valid iff both counts>0.
// ---------------------------------------------------------------------------
__global__ void finalize(const int* __restrict__ gcnt, const int* __restrict__ pcnt,
                         const float* __restrict__ gsum, const float* __restrict__ psum,
                         float* __restrict__ out) {
    float sum = 0.0f;
    int nvalid = 0;
    for (int s = 0; s < NSLICE; ++s) {
        int ng = gcnt[s];
        int np_ = pcnt[s];
        if (ng > 0 && np_ > 0) {
            float ahd = 0.5f * (gsum[s] / (float)ng + psum[s] / (float)np_);
            sum += 1.0f - 1.0f / (1.0f + ahd);
            nvalid++;
        }
    }
    out[0] = nvalid ? (sum / (float)nvalid) : NAN;
}

// ---------------------------------------------------------------------------
// Workspace layout (bytes):
//   [0,        512K)     gpts : 16 x 4096 float2
//   [512K,     1M)       ppts : 16 x 4096 float2
//   [1M,       1.25M)    bm   : 2 x 16 x 256 x 4 u64
//   [1310720,  1835008)  part : 32 x 4096 uint (min d2 per query)
//   [1835008, +64)       gcnt : 16 int
//   [1835072, +64)       pcnt : 16 int
//   [1835136, +64)       gsum : 16 float
//   [1835200, +64)       psum : 16 float
// ---------------------------------------------------------------------------
extern "C" void kernel_launch(void* const* d_in, const int* in_sizes, int n_in,
                              void* d_out, int out_size, void* d_ws, size_t ws_size,
                              hipStream_t stream) {
    const float* gth = (const float*)d_in[0];
    const float* pred = (const float*)d_in[1];
    float* out = (float*)d_out;
    char* ws = (char*)d_ws;

    float2* gpts = (float2*)(ws);
    float2* ppts = (float2*)(ws + 524288);
    u64* bm = (u64*)(ws + 1048576);
    unsigned* part = (unsigned*)(ws + 1310720);
    int* gcnt = (int*)(ws + 1835008);
    int* pcnt = (int*)(ws + 1835072);
    float* gsum = (float*)(ws + 1835136);
    float* psum = (float*)(ws + 1835200);

    binarize_pack<<<8192, 256, 0, stream>>>(gth, pred, bm, part);
    edge_compact2<<<32, 256, 0, stream>>>(bm, gpts, ppts, gcnt, pcnt);
    mindist_part<<<NSLICE * 2 * NQB * NTB, 256, 0, stream>>>(gpts, ppts, gcnt, pcnt, part);
    combine<<<32, 256, 0, stream>>>(gcnt, pcnt, part, gsum, psum);
    finalize<<<1, 1, 0, stream>>>(gcnt, pcnt, gsum, psum, out);
}

// Round 4
// 63.983 us; speedup vs baseline: 1.3625x; 1.3625x over previous
//
#include <hip/hip_runtime.h>
#include <math.h>

#define HH 256
#define WW 256
#define HWSZ (HH * WW)
#define KE 4096
#define NSLICE 16

typedef unsigned long long u64;

// ---------------------------------------------------------------------------
// Kernel 1: binarize + bit-pack. One block per image row (2 x 16 x 256 =
// 8192 blocks). Lane thresholds one pixel; ballot packs 64 cols -> u64.
// bm layout: [tensor][slice][row][word4].
// ---------------------------------------------------------------------------
__global__ void __launch_bounds__(256) binarize_pack(
        const float* __restrict__ gth, const float* __restrict__ pred,
        u64* __restrict__ bm) {
    int b = blockIdx.x;                 // tensor*4096 + slice*256 + row
    int tensor = b >> 12;
    int sr = b & 4095;
    const float* img = tensor ? pred : gth;
    float v = img[sr * WW + threadIdx.x];
    u64 bal = __ballot(v > 0.5f);
    int lane = threadIdx.x & 63;
    int wave = threadIdx.x >> 6;
    if (lane == 0) bm[(size_t)b * 4 + wave] = bal;
}

// ---------------------------------------------------------------------------
// Kernel 2: bitwise edge detect + ordered compaction + truncated edge bitmap.
// 32 blocks (tensor, slice), thread = row. Erosion with +inf padding:
//   vert  = rowAbove & row & rowBelow      (OOB row = all-ones)
//   erode = vert & shl1 & shr1             (OOB col carry-in = 1)
//   edge  = row & ~erode
// Row popcounts -> block scan -> ordered point writes (row-major order ==
// jnp.nonzero). Also writes ebm = edge bitmap with bits of row-major rank
// >= KE cleared (the reference only ever sees the first KE points as
// targets). cnt = FULL count (the divisor).
// ---------------------------------------------------------------------------
__global__ void __launch_bounds__(256) edge_compact3(
        const u64* __restrict__ bm,
        float2* __restrict__ gpts, float2* __restrict__ ppts,
        u64* __restrict__ ebm,
        int* __restrict__ gcnt, int* __restrict__ pcnt) {
    int b = blockIdx.x;                 // 0..31  (tensor*16 + slice)
    int tensor = b >> 4;
    int slice = b & 15;
    const u64* rm = bm + (size_t)(tensor * 4096 + slice * 256) * 4;
    float2* pts = (tensor ? ppts : gpts) + slice * KE;
    int* cnt = (tensor ? pcnt : gcnt) + slice;
    u64* eb = ebm + (size_t)b * 1024;   // 256 rows x 4 words

    int row = threadIdx.x;
    u64 vc[4], va[4], vb[4];
#pragma unroll
    for (int w = 0; w < 4; ++w) {
        vc[w] = rm[row * 4 + w];
        va[w] = (row > 0) ? rm[(row - 1) * 4 + w] : ~0ull;
        vb[w] = (row < HH - 1) ? rm[(row + 1) * 4 + w] : ~0ull;
    }
    u64 vert[4];
#pragma unroll
    for (int w = 0; w < 4; ++w) vert[w] = va[w] & vc[w] & vb[w];
    u64 e[4];
#pragma unroll
    for (int w = 0; w < 4; ++w) {
        u64 left  = (vert[w] << 1) | ((w > 0) ? (vert[w - 1] >> 63) : 1ull);
        u64 right = (vert[w] >> 1) | (((w < 3) ? (vert[w + 1] & 1ull) : 1ull) << 63);
        e[w] = vc[w] & ~(vert[w] & left & right);
    }
    int mycnt = __popcll(e[0]) + __popcll(e[1]) + __popcll(e[2]) + __popcll(e[3]);

    __shared__ int sc[256];
    sc[row] = mycnt;
    __syncthreads();
    for (int d = 1; d < 256; d <<= 1) {
        int v = (row >= d) ? sc[row - d] : 0;
        __syncthreads();
        sc[row] += v;
        __syncthreads();
    }
    int off = sc[row] - mycnt;          // exclusive prefix (row-major rank)

    // Truncated edge bitmap: keep only bits with rank < KE.
    int rem = KE - off;                 // how many of this row's bits survive
    u64 t[4];
    if (rem >= mycnt) {
#pragma unroll
        for (int w = 0; w < 4; ++w) t[w] = e[w];
    } else if (rem <= 0) {
#pragma unroll
        for (int w = 0; w < 4; ++w) t[w] = 0ull;
    } else {
        int k = rem;
#pragma unroll
        for (int w = 0; w < 4; ++w) {
            int pc = __popcll(e[w]);
            if (k >= pc) { t[w] = e[w]; k -= pc; }
            else {
                u64 bits = e[w], keep = 0ull;
                for (int i = 0; i < k; ++i) {
                    u64 low = bits & (~bits + 1ull);
                    keep |= low;
                    bits ^= low;
                }
                t[w] = keep;
                k = 0;
            }
        }
    }
#pragma unroll
    for (int w = 0; w < 4; ++w) eb[row * 4 + w] = t[w];

    // Ordered point-list writes (queries).
    int o = off;
#pragma unroll
    for (int w = 0; w < 4; ++w) {
        u64 bits = e[w];
        while (bits) {
            int l = __ffsll((long long)bits) - 1;
            bits &= bits - 1;
            if (o < KE) pts[o] = make_float2((float)row, (float)(w * 64 + l));
            ++o;
        }
    }
    if (row == HH - 1) *cnt = sc[HH - 1];
}

// ---------------------------------------------------------------------------
// Nearest set bit in a 256-bit row (4 u64 words) to column c.
// Returns |dc|, or 4096 sentinel if the row is empty on that side.
// ---------------------------------------------------------------------------
__device__ __forceinline__ int row_dc(const u64* __restrict__ w, int c) {
    int cw = c >> 6, cb = c & 63;
    int right = 1 << 12;
    u64 m = w[cw] >> cb;                     // bit c -> position 0
    if (m) right = __ffsll((long long)m) - 1;
    else {
        for (int k = cw + 1; k < 4; ++k)
            if (w[k]) { right = (k << 6) + __ffsll((long long)w[k]) - 1 - c; break; }
    }
    int left = 1 << 12;
    u64 m2 = w[cw] << (63 - cb);             // bit c -> position 63
    if (m2) left = __clzll((long long)m2);
    else {
        for (int k = cw - 1; k >= 0; --k)
            if (w[k]) { left = c - ((k << 6) + 63 - __clzll((long long)w[k])); break; }
    }
    return min(left, right);
}

// ---------------------------------------------------------------------------
// Kernel 3: per-query nearest-neighbor via expanding-ring bitmap search.
// Grid = 16 slices x 2 dirs x 16 query chunks = 512 blocks, 256 threads.
// Target edge bitmap (truncated at KE) staged in LDS with row stride 5 u64
// (breaks the rows%4 bank aliasing). Ring terminates when dr^2 >= best.
// Exact integer d2 -> sqrt matches reference bitwise. Per-block partial sum
// (fixed chunking, no atomics -> deterministic).
// ---------------------------------------------------------------------------
__global__ void __launch_bounds__(256) nn_search(
        const float2* __restrict__ gpts, const float2* __restrict__ ppts,
        const u64* __restrict__ ebm,
        const int* __restrict__ gcnt, const int* __restrict__ pcnt,
        float* __restrict__ partial) {
    int b = blockIdx.x;
    int chunk = b & 15;
    int dir = (b >> 4) & 1;             // 0: g->p, 1: p->g
    int slice = b >> 5;
    int sd = slice * 2 + dir;
    int tid = threadIdx.x;

    int qfull = dir ? pcnt[slice] : gcnt[slice];
    int tfull = dir ? gcnt[slice] : pcnt[slice];
    int qc = min(qfull, KE);
    if (chunk * 256 >= qc || tfull == 0) {
        if (tid == 0) partial[sd * 16 + chunk] = 0.0f;
        return;
    }

    const float2* q = (dir ? ppts : gpts) + slice * KE;
    int tt = dir ? 0 : 1;               // target tensor: pred for g->p, gth for p->g
    const u64* tb = ebm + (size_t)(tt * 16 + slice) * 1024;

    __shared__ u64 lbm[256 * 5];        // row stride 5 words (bank de-alias)
    __shared__ float red[256];
    for (int i = tid; i < 1024; i += 256) {
        int r = i >> 2, w = i & 3;
        lbm[r * 5 + w] = tb[i];
    }
    __syncthreads();

    int qi = chunk * 256 + tid;
    float val = 0.0f;
    if (qi < qc) {
        float2 qp = q[qi];
        int r = (int)qp.x, c = (int)qp.y;
        int best = 0x7fffffff;
        for (int d = 0; d < HH; ++d) {
            if (d * d >= best) break;
            int rp = r + d;
            if (rp < HH) {
                int dc = row_dc(&lbm[rp * 5], c);
                best = min(best, d * d + dc * dc);
            }
            if (d > 0) {
                int rm2 = r - d;
                if (rm2 >= 0) {
                    int dc = row_dc(&lbm[rm2 * 5], c);
                    best = min(best, d * d + dc * dc);
                }
            }
        }
        val = sqrtf((float)best);
    }
    red[tid] = val;
    __syncthreads();
    for (int s = 128; s > 0; s >>= 1) {
        if (tid < s) red[tid] += red[tid + s];
        __syncthreads();
    }
    if (tid == 0) partial[sd * 16 + chunk] = red[0];
}

// ---------------------------------------------------------------------------
// Kernel 4: fold 512 partials -> per-slice ahd -> loss -> nanmean.
// 1 block x 512 threads; 16-lane shuffle groups; slice valid iff both
// counts > 0 (reference yields NaN otherwise, nanmean skips).
// ---------------------------------------------------------------------------
__global__ void __launch_bounds__(512) finalize2(
        const int* __restrict__ gcnt, const int* __restrict__ pcnt,
        const float* __restrict__ partial, float* __restrict__ out) {
    int tid = threadIdx.x;              // sd*16 + chunk
    float v = partial[tid];
    v += __shfl_xor(v, 1, 16);
    v += __shfl_xor(v, 2, 16);
    v += __shfl_xor(v, 4, 16);
    v += __shfl_xor(v, 8, 16);
    __shared__ float sdsum[32];
    if ((tid & 15) == 0) sdsum[tid >> 4] = v;
    __syncthreads();
    if (tid == 0) {
        float sum = 0.0f;
        int nvalid = 0;
        for (int s = 0; s < NSLICE; ++s) {
            int ng = gcnt[s];
            int np_ = pcnt[s];
            if (ng > 0 && np_ > 0) {
                float ahd = 0.5f * (sdsum[s * 2 + 0] / (float)ng +
                                    sdsum[s * 2 + 1] / (float)np_);
                sum += 1.0f - 1.0f / (1.0f + ahd);
                nvalid++;
            }
        }
        out[0] = nvalid ? (sum / (float)nvalid) : NAN;
    }
}

// ---------------------------------------------------------------------------
// Workspace layout (bytes):
//   [0,       256K)   bm     : 2 x 16 x 256 x 4 u64   (mask bitmaps)
//   [256K,    512K)   ebm    : 2 x 16 x 256 x 4 u64   (truncated edge bitmaps)
//   [512K,    1M)     gpts   : 16 x 4096 float2
//   [1M,      1.5M)   ppts   : 16 x 4096 float2
//   [1572864, +64)    gcnt   : 16 int
//   [1572928, +64)    pcnt   : 16 int
//   [1572992, +2K)    partial: 512 float
// ---------------------------------------------------------------------------
extern "C" void kernel_launch(void* const* d_in, const int* in_sizes, int n_in,
                              void* d_out, int out_size, void* d_ws, size_t ws_size,
                              hipStream_t stream) {
    const float* gth = (const float*)d_in[0];
    const float* pred = (const float*)d_in[1];
    float* out = (float*)d_out;
    char* ws = (char*)d_ws;

    u64* bm = (u64*)(ws);
    u64* ebm = (u64*)(ws + 262144);
    float2* gpts = (float2*)(ws + 524288);
    float2* ppts = (float2*)(ws + 1048576);
    int* gcnt = (int*)(ws + 1572864);
    int* pcnt = (int*)(ws + 1572928);
    float* partial = (float*)(ws + 1572992);

    binarize_pack<<<8192, 256, 0, stream>>>(gth, pred, bm);
    edge_compact3<<<32, 256, 0, stream>>>(bm, gpts, ppts, ebm, gcnt, pcnt);
    nn_search<<<512, 256, 0, stream>>>(gpts, ppts, ebm, gcnt, pcnt, partial);
    finalize2<<<1, 512, 0, stream>>>(gcnt, pcnt, partial, out);
}

// Round 5
// 47.259 us; speedup vs baseline: 1.8447x; 1.3539x over previous
//
#include <hip/hip_runtime.h>
#include <math.h>

#define HH 256
#define WW 256
#define HWSZ (HH * WW)
#define KE 4096
#define NSLICE 16
#define NCH 64                 // query chunks of 64 per (slice,dir)
#define GSENT 1024             // empty-column sentinel: 1024^2 > max real d2 (130050)

typedef unsigned long long u64;
typedef unsigned short u16;

// ---------------------------------------------------------------------------
// Kernel 1: binarize + bit-pack. One block per image row (2 x 16 x 256 =
// 8192 blocks). Lane thresholds one pixel; ballot packs 64 cols -> u64.
// bm layout: [tensor][slice][row][word4].
// ---------------------------------------------------------------------------
__global__ void __launch_bounds__(256) binarize_pack(
        const float* __restrict__ gth, const float* __restrict__ pred,
        u64* __restrict__ bm) {
    int b = blockIdx.x;                 // tensor*4096 + slice*256 + row
    int tensor = b >> 12;
    int sr = b & 4095;
    const float* img = tensor ? pred : gth;
    float v = img[sr * WW + threadIdx.x];
    u64 bal = __ballot(v > 0.5f);
    int lane = threadIdx.x & 63;
    int wave = threadIdx.x >> 6;
    if (lane == 0) bm[(size_t)b * 4 + wave] = bal;
}

// ---------------------------------------------------------------------------
// Kernel 2: edge detect + ordered compaction + vertical EDT (fused).
// 32 blocks (tensor,slice) x 256 threads.
// Phase 1 (thread=row): bitwise erosion / edge bits, block scan, ordered
//   point writes (row-major == jnp.nonzero), truncated edge bitmap -> LDS.
// Phase 2 (thread=col): vertical distance field G[r][c] = min |r-r'| over
//   set bits of column c (down scan then up scan), u16, global (L2-hot).
//   Empty column -> GSENT.
// ---------------------------------------------------------------------------
__global__ void __launch_bounds__(256) edge_edt(
        const u64* __restrict__ bm,
        float2* __restrict__ gpts, float2* __restrict__ ppts,
        int* __restrict__ gcnt, int* __restrict__ pcnt,
        u16* __restrict__ G16) {
    int b = blockIdx.x;                 // 0..31  (tensor*16 + slice)
    int tensor = b >> 4;
    int slice = b & 15;
    const u64* rm = bm + (size_t)(tensor * 4096 + slice * 256) * 4;
    float2* pts = (tensor ? ppts : gpts) + slice * KE;
    int* cnt = (tensor ? pcnt : gcnt) + slice;

    __shared__ int sc[256];
    __shared__ u64 ebl[1024];           // truncated edge bitmap, [row][word4]

    int row = threadIdx.x;
    u64 vc[4], va[4], vb[4];
#pragma unroll
    for (int w = 0; w < 4; ++w) {
        vc[w] = rm[row * 4 + w];
        va[w] = (row > 0) ? rm[(row - 1) * 4 + w] : ~0ull;
        vb[w] = (row < HH - 1) ? rm[(row + 1) * 4 + w] : ~0ull;
    }
    u64 vert[4];
#pragma unroll
    for (int w = 0; w < 4; ++w) vert[w] = va[w] & vc[w] & vb[w];
    u64 e[4];
#pragma unroll
    for (int w = 0; w < 4; ++w) {
        u64 left  = (vert[w] << 1) | ((w > 0) ? (vert[w - 1] >> 63) : 1ull);
        u64 right = (vert[w] >> 1) | (((w < 3) ? (vert[w + 1] & 1ull) : 1ull) << 63);
        e[w] = vc[w] & ~(vert[w] & left & right);
    }
    int mycnt = __popcll(e[0]) + __popcll(e[1]) + __popcll(e[2]) + __popcll(e[3]);

    sc[row] = mycnt;
    __syncthreads();
    for (int d = 1; d < 256; d <<= 1) {
        int v = (row >= d) ? sc[row - d] : 0;
        __syncthreads();
        sc[row] += v;
        __syncthreads();
    }
    int off = sc[row] - mycnt;          // exclusive prefix (row-major rank)

    // Truncated edge bitmap (only bits with rank < KE) -> LDS.
    int rem = KE - off;
    u64 t[4];
    if (rem >= mycnt) {
#pragma unroll
        for (int w = 0; w < 4; ++w) t[w] = e[w];
    } else if (rem <= 0) {
#pragma unroll
        for (int w = 0; w < 4; ++w) t[w] = 0ull;
    } else {
        int k = rem;
#pragma unroll
        for (int w = 0; w < 4; ++w) {
            int pc = __popcll(e[w]);
            if (k >= pc) { t[w] = e[w]; k -= pc; }
            else {
                u64 bits = e[w], keep = 0ull;
                for (int i = 0; i < k; ++i) {
                    u64 low = bits & (~bits + 1ull);
                    keep |= low;
                    bits ^= low;
                }
                t[w] = keep;
                k = 0;
            }
        }
    }
#pragma unroll
    for (int w = 0; w < 4; ++w) ebl[row * 4 + w] = t[w];

    // Ordered point-list writes (queries; first KE in row-major order).
    int o = off;
#pragma unroll
    for (int w = 0; w < 4; ++w) {
        u64 bits = e[w];
        while (bits) {
            int l = __ffsll((long long)bits) - 1;
            bits &= bits - 1;
            if (o < KE) pts[o] = make_float2((float)row, (float)(w * 64 + l));
            ++o;
        }
    }
    if (row == HH - 1) *cnt = sc[HH - 1];
    __syncthreads();

    // ---- Phase 2: vertical EDT, thread = column ----
    int c = threadIdx.x;
    int cw = c >> 6, cb = c & 63;
    u16* G = G16 + (size_t)b * HWSZ;
    int g = GSENT;
    for (int r = 0; r < HH; ++r) {
        int bit = (int)((ebl[r * 4 + cw] >> cb) & 1ull);
        g = bit ? 0 : min(g + 1, GSENT);
        G[r * WW + c] = (u16)g;         // coalesced u16 store
    }
    __syncthreads();                    // drain stores (vmcnt0) before re-read
    int gu = GSENT;
    for (int r = HH - 1; r >= 0; --r) {
        int bit = (int)((ebl[r * 4 + cw] >> cb) & 1ull);
        gu = bit ? 0 : min(gu + 1, GSENT);
        int gf = min((int)G[r * WW + c], gu);
        G[r * WW + c] = (u16)gf;
    }
}

// ---------------------------------------------------------------------------
// Kernel 3: per-query NN distance via column scan of the vertical EDT.
// Grid = 32 (slice,dir) x 64 chunks of 64 queries = 2048 blocks x 64 thr.
// d2(q) = min_{c'} ( (c-c')^2 + G[r][c']^2 ) -- exact integers, fixed 256
// iterations, 32 independent int4 loads -> deep MLP, no divergence.
// Wave-level sum -> one partial per block (deterministic).
// ---------------------------------------------------------------------------
__global__ void __launch_bounds__(64) nn_gather(
        const float2* __restrict__ gpts, const float2* __restrict__ ppts,
        const int* __restrict__ gcnt, const int* __restrict__ pcnt,
        const u16* __restrict__ G16, float* __restrict__ partial) {
    int b = blockIdx.x;                 // sd*NCH + chunk
    int chunk = b & (NCH - 1);
    int sd = b >> 6;                    // slice*2 + dir
    int dir = sd & 1;
    int slice = sd >> 1;
    int tid = threadIdx.x;

    int qfull = dir ? pcnt[slice] : gcnt[slice];
    int qc = min(qfull, KE);
    int qi = chunk * 64 + tid;

    float val = 0.0f;
    if (qi < qc) {
        const float2* q = (dir ? ppts : gpts) + slice * KE;
        int tt = dir ? 0 : 1;           // target map tensor
        const u16* G = G16 + (size_t)(tt * 16 + slice) * HWSZ;
        float2 qp = q[qi];
        int r = (int)qp.x, c = (int)qp.y;
        const int4* grow = (const int4*)(G + r * WW);   // 256 u16 = 32 int4
        int m = 0x7fffffff;
#pragma unroll
        for (int j = 0; j < 32; ++j) {
            int4 v = grow[j];
            int base = j * 8;
#define STEP(word, k0)                                                      \
            {                                                               \
                int g0 = (word) & 0xffff;                                   \
                int g1 = (int)(((unsigned)(word)) >> 16);                   \
                int dc0 = c - (base + k0);                                  \
                int dc1 = c - (base + k0 + 1);                              \
                m = min(m, dc0 * dc0 + g0 * g0);                            \
                m = min(m, dc1 * dc1 + g1 * g1);                            \
            }
            STEP(v.x, 0) STEP(v.y, 2) STEP(v.z, 4) STEP(v.w, 6)
#undef STEP
        }
        val = sqrtf((float)m);
    }
    // 64-lane wave sum
    for (int s = 32; s > 0; s >>= 1) val += __shfl_xor(val, s, 64);
    if (tid == 0) partial[b] = val;
}

// ---------------------------------------------------------------------------
// Kernel 4: fold 2048 partials -> per-slice ahd -> loss -> nanmean.
// 1 block x 512 threads; thread t sums partial[4t..4t+3] (same sd since
// 64 chunks/sd), 16-lane shuffle groups -> sdsum[32] -> scalar epilogue.
// ---------------------------------------------------------------------------
__global__ void __launch_bounds__(512) finalize3(
        const int* __restrict__ gcnt, const int* __restrict__ pcnt,
        const float* __restrict__ partial, float* __restrict__ out) {
    int tid = threadIdx.x;
    float v = partial[tid * 4] + partial[tid * 4 + 1] +
              partial[tid * 4 + 2] + partial[tid * 4 + 3];
    v += __shfl_xor(v, 1, 16);
    v += __shfl_xor(v, 2, 16);
    v += __shfl_xor(v, 4, 16);
    v += __shfl_xor(v, 8, 16);
    __shared__ float sdsum[32];
    if ((tid & 15) == 0) sdsum[tid >> 4] = v;
    __syncthreads();
    if (tid == 0) {
        float sum = 0.0f;
        int nvalid = 0;
        for (int s = 0; s < NSLICE; ++s) {
            int ng = gcnt[s];
            int np_ = pcnt[s];
            if (ng > 0 && np_ > 0) {
                float ahd = 0.5f * (sdsum[s * 2 + 0] / (float)ng +
                                    sdsum[s * 2 + 1] / (float)np_);
                sum += 1.0f - 1.0f / (1.0f + ahd);
                nvalid++;
            }
        }
        out[0] = nvalid ? (sum / (float)nvalid) : NAN;
    }
}

// ---------------------------------------------------------------------------
// Workspace layout (bytes):
//   [0,       256K)     bm     : 2 x 16 x 256 x 4 u64   (mask bitmaps)
//   [262144,  786432)   gpts   : 16 x 4096 float2
//   [786432,  1310720)  ppts   : 16 x 4096 float2
//   [1310720, 5505024)  G16    : 32 maps x 256 x 256 u16 (vertical EDT)
//   [5505024, +64)      gcnt   : 16 int
//   [5505088, +64)      pcnt   : 16 int
//   [5505152, +8K)      partial: 2048 float
// ---------------------------------------------------------------------------
extern "C" void kernel_launch(void* const* d_in, const int* in_sizes, int n_in,
                              void* d_out, int out_size, void* d_ws, size_t ws_size,
                              hipStream_t stream) {
    const float* gth = (const float*)d_in[0];
    const float* pred = (const float*)d_in[1];
    float* out = (float*)d_out;
    char* ws = (char*)d_ws;

    u64* bm = (u64*)(ws);
    float2* gpts = (float2*)(ws + 262144);
    float2* ppts = (float2*)(ws + 786432);
    u16* G16 = (u16*)(ws + 1310720);
    int* gcnt = (int*)(ws + 5505024);
    int* pcnt = (int*)(ws + 5505088);
    float* partial = (float*)(ws + 5505152);

    binarize_pack<<<8192, 256, 0, stream>>>(gth, pred, bm);
    edge_edt<<<32, 256, 0, stream>>>(bm, gpts, ppts, gcnt, pcnt, G16);
    nn_gather<<<NSLICE * 2 * NCH, 64, 0, stream>>>(gpts, ppts, gcnt, pcnt, G16, partial);
    finalize3<<<1, 512, 0, stream>>>(gcnt, pcnt, partial, out);
}

// Round 6
// 46.743 us; speedup vs baseline: 1.8651x; 1.0110x over previous
//
#include <hip/hip_runtime.h>
#include <math.h>

#define HH 256
#define WW 256
#define HWSZ (HH * WW)
#define KE 4096
#define NSLICE 16
#define NCH 64                 // query chunks of 64 per (slice,dir)
#define GSENT 1024             // empty-column sentinel: 1024^2 > max real d2 (130050)
#define RPB 32                 // rows per edt_vert block

typedef unsigned long long u64;
typedef unsigned short u16;

// ---------------------------------------------------------------------------
// Kernel 1: binarize + bit-pack. One block per image row (2 x 16 x 256 =
// 8192 blocks). Lane thresholds one pixel; ballot packs 64 cols -> u64.
// bm layout: [tensor][slice][row][word4].
// ---------------------------------------------------------------------------
__global__ void __launch_bounds__(256) binarize_pack(
        const float* __restrict__ gth, const float* __restrict__ pred,
        u64* __restrict__ bm) {
    int b = blockIdx.x;                 // tensor*4096 + slice*256 + row
    int tensor = b >> 12;
    int sr = b & 4095;
    const float* img = tensor ? pred : gth;
    float v = img[sr * WW + threadIdx.x];
    u64 bal = __ballot(v > 0.5f);
    int lane = threadIdx.x & 63;
    int wave = threadIdx.x >> 6;
    if (lane == 0) bm[(size_t)b * 4 + wave] = bal;
}

// ---------------------------------------------------------------------------
// Kernel 2: bitwise edge detect + ordered compaction + truncated edge bitmap
// (round-4 proven version). 32 blocks (tensor,slice), thread = row.
//   vert  = rowAbove & row & rowBelow      (OOB row = all-ones)
//   erode = vert & shl1 & shr1             (OOB col carry-in = 1)
//   edge  = row & ~erode
// Row popcounts -> block scan -> ordered point writes (row-major ==
// jnp.nonzero). ebm gets bits of row-major rank < KE only (the reference
// only ever sees the first KE points as targets). cnt = FULL count.
// ---------------------------------------------------------------------------
__global__ void __launch_bounds__(256) edge_compact(
        const u64* __restrict__ bm,
        float2* __restrict__ gpts, float2* __restrict__ ppts,
        u64* __restrict__ ebm,
        int* __restrict__ gcnt, int* __restrict__ pcnt) {
    int b = blockIdx.x;                 // 0..31  (tensor*16 + slice)
    int tensor = b >> 4;
    int slice = b & 15;
    const u64* rm = bm + (size_t)(tensor * 4096 + slice * 256) * 4;
    float2* pts = (tensor ? ppts : gpts) + slice * KE;
    int* cnt = (tensor ? pcnt : gcnt) + slice;
    u64* eb = ebm + (size_t)b * 1024;   // 256 rows x 4 words

    int row = threadIdx.x;
    u64 vc[4], va[4], vb[4];
#pragma unroll
    for (int w = 0; w < 4; ++w) {
        vc[w] = rm[row * 4 + w];
        va[w] = (row > 0) ? rm[(row - 1) * 4 + w] : ~0ull;
        vb[w] = (row < HH - 1) ? rm[(row + 1) * 4 + w] : ~0ull;
    }
    u64 vert[4];
#pragma unroll
    for (int w = 0; w < 4; ++w) vert[w] = va[w] & vc[w] & vb[w];
    u64 e[4];
#pragma unroll
    for (int w = 0; w < 4; ++w) {
        u64 left  = (vert[w] << 1) | ((w > 0) ? (vert[w - 1] >> 63) : 1ull);
        u64 right = (vert[w] >> 1) | (((w < 3) ? (vert[w + 1] & 1ull) : 1ull) << 63);
        e[w] = vc[w] & ~(vert[w] & left & right);
    }
    int mycnt = __popcll(e[0]) + __popcll(e[1]) + __popcll(e[2]) + __popcll(e[3]);

    __shared__ int sc[256];
    sc[row] = mycnt;
    __syncthreads();
    for (int d = 1; d < 256; d <<= 1) {
        int v = (row >= d) ? sc[row - d] : 0;
        __syncthreads();
        sc[row] += v;
        __syncthreads();
    }
    int off = sc[row] - mycnt;          // exclusive prefix (row-major rank)

    // Truncated edge bitmap: keep only bits with rank < KE.
    int rem = KE - off;
    u64 t[4];
    if (rem >= mycnt) {
#pragma unroll
        for (int w = 0; w < 4; ++w) t[w] = e[w];
    } else if (rem <= 0) {
#pragma unroll
        for (int w = 0; w < 4; ++w) t[w] = 0ull;
    } else {
        int k = rem;
#pragma unroll
        for (int w = 0; w < 4; ++w) {
            int pc = __popcll(e[w]);
            if (k >= pc) { t[w] = e[w]; k -= pc; }
            else {
                u64 bits = e[w], keep = 0ull;
                for (int i = 0; i < k; ++i) {
                    u64 low = bits & (~bits + 1ull);
                    keep |= low;
                    bits ^= low;
                }
                t[w] = keep;
                k = 0;
            }
        }
    }
#pragma unroll
    for (int w = 0; w < 4; ++w) eb[row * 4 + w] = t[w];

    // Ordered point-list writes (queries; first KE in row-major order).
    int o = off;
#pragma unroll
    for (int w = 0; w < 4; ++w) {
        u64 bits = e[w];
        while (bits) {
            int l = __ffsll((long long)bits) - 1;
            bits &= bits - 1;
            if (o < KE) pts[o] = make_float2((float)row, (float)(w * 64 + l));
            ++o;
        }
    }
    if (row == HH - 1) *cnt = sc[HH - 1];
}

// ---------------------------------------------------------------------------
// word_dist: distance from position p (may be <0 or >63) to the nearest set
// bit of w; GSENT if w empty. ~10 ops, short divergence only.
// ---------------------------------------------------------------------------
__device__ __forceinline__ int word_dist(u64 w, int p) {
    if (w == 0) return GSENT;
    int lo = __ffsll((long long)w) - 1;    // lowest set bit
    int hi = 63 - __clzll((long long)w);   // highest set bit
    if (p <= lo) return lo - p;
    if (p >= hi) return p - hi;
    u64 up = w >> p;                        // bits >= p (nonzero: hi > p)
    int du = __ffsll((long long)up) - 1;
    u64 dn = w << (63 - p);                 // bits <= p (nonzero: lo < p)
    int dd = __clzll((long long)dn);
    return min(du, dd);
}

// ---------------------------------------------------------------------------
// Kernel 3: vertical EDT, fully parallel (no serial column scan).
// Grid = 32 maps x 8 row-blocks = 256 blocks x 256 threads. Stage the 8 KB
// edge bitmap in LDS (uniform-address reads -> broadcast). Thread = column:
// gather the column's 256 bits into 4 registers, then for each of the
// block's 32 rows compute G[r][c] = min over 4 words of word_dist.
// Stores coalesced (threads = consecutive c).
// ---------------------------------------------------------------------------
__global__ void __launch_bounds__(256) edt_vert(
        const u64* __restrict__ ebm, u16* __restrict__ G16) {
    int map = blockIdx.x >> 3;
    int rblk = blockIdx.x & 7;
    const u64* eb = ebm + (size_t)map * 1024;
    u16* G = G16 + (size_t)map * HWSZ;

    __shared__ u64 ebl[1024];
    int tid = threadIdx.x;
    for (int i = tid; i < 1024; i += 256) ebl[i] = eb[i];
    __syncthreads();

    int c = tid, cw = c >> 6, cb = c & 63;
    u64 w0 = 0, w1 = 0, w2 = 0, w3 = 0;
#pragma unroll 4
    for (int r = 0; r < 64; ++r) {
        w0 |= ((ebl[(r      ) * 4 + cw] >> cb) & 1ull) << r;
        w1 |= ((ebl[(r +  64) * 4 + cw] >> cb) & 1ull) << r;
        w2 |= ((ebl[(r + 128) * 4 + cw] >> cb) & 1ull) << r;
        w3 |= ((ebl[(r + 192) * 4 + cw] >> cb) & 1ull) << r;
    }

    int r0 = rblk * RPB;
#pragma unroll 4
    for (int i = 0; i < RPB; ++i) {
        int r = r0 + i;
        int d = word_dist(w0, r);
        d = min(d, word_dist(w1, r - 64));
        d = min(d, word_dist(w2, r - 128));
        d = min(d, word_dist(w3, r - 192));
        G[r * WW + c] = (u16)min(d, GSENT);
    }
}

// ---------------------------------------------------------------------------
// Kernel 4: per-query NN distance via column scan of the vertical EDT.
// Grid = 32 (slice,dir) x 64 chunks of 64 queries = 2048 blocks x 64 thr.
// d2(q) = min_{c'} ( (c-c')^2 + G[r][c']^2 ) -- exact integers, fixed 256
// candidates, 32 independent int4 loads -> deep MLP, no divergence.
// ---------------------------------------------------------------------------
__global__ void __launch_bounds__(64) nn_gather(
        const float2* __restrict__ gpts, const float2* __restrict__ ppts,
        const int* __restrict__ gcnt, const int* __restrict__ pcnt,
        const u16* __restrict__ G16, float* __restrict__ partial) {
    int b = blockIdx.x;                 // sd*NCH + chunk
    int chunk = b & (NCH - 1);
    int sd = b >> 6;                    // slice*2 + dir
    int dir = sd & 1;
    int slice = sd >> 1;
    int tid = threadIdx.x;

    int qfull = dir ? pcnt[slice] : gcnt[slice];
    int qc = min(qfull, KE);
    int qi = chunk * 64 + tid;

    float val = 0.0f;
    if (qi < qc) {
        const float2* q = (dir ? ppts : gpts) + slice * KE;
        int tt = dir ? 0 : 1;           // target map tensor
        const u16* G = G16 + (size_t)(tt * 16 + slice) * HWSZ;
        float2 qp = q[qi];
        int r = (int)qp.x, c = (int)qp.y;
        const int4* grow = (const int4*)(G + r * WW);   // 256 u16 = 32 int4
        int m = 0x7fffffff;
#pragma unroll
        for (int j = 0; j < 32; ++j) {
            int4 v = grow[j];
            int base = j * 8;
#define STEP(word, k0)                                                      \
            {                                                               \
                int g0 = (word) & 0xffff;                                   \
                int g1 = (int)(((unsigned)(word)) >> 16);                   \
                int dc0 = c - (base + k0);                                  \
                int dc1 = c - (base + k0 + 1);                              \
                m = min(m, dc0 * dc0 + g0 * g0);                            \
                m = min(m, dc1 * dc1 + g1 * g1);                            \
            }
            STEP(v.x, 0) STEP(v.y, 2) STEP(v.z, 4) STEP(v.w, 6)
#undef STEP
        }
        val = sqrtf((float)m);
    }
    for (int s = 32; s > 0; s >>= 1) val += __shfl_xor(val, s, 64);
    if (tid == 0) partial[b] = val;
}

// ---------------------------------------------------------------------------
// Kernel 5: fold 2048 partials -> per-slice ahd -> loss -> nanmean.
// ---------------------------------------------------------------------------
__global__ void __launch_bounds__(512) finalize3(
        const int* __restrict__ gcnt, const int* __restrict__ pcnt,
        const float* __restrict__ partial, float* __restrict__ out) {
    int tid = threadIdx.x;
    float v = partial[tid * 4] + partial[tid * 4 + 1] +
              partial[tid * 4 + 2] + partial[tid * 4 + 3];
    v += __shfl_xor(v, 1, 16);
    v += __shfl_xor(v, 2, 16);
    v += __shfl_xor(v, 4, 16);
    v += __shfl_xor(v, 8, 16);
    __shared__ float sdsum[32];
    if ((tid & 15) == 0) sdsum[tid >> 4] = v;
    __syncthreads();
    if (tid == 0) {
        float sum = 0.0f;
        int nvalid = 0;
        for (int s = 0; s < NSLICE; ++s) {
            int ng = gcnt[s];
            int np_ = pcnt[s];
            if (ng > 0 && np_ > 0) {
                float ahd = 0.5f * (sdsum[s * 2 + 0] / (float)ng +
                                    sdsum[s * 2 + 1] / (float)np_);
                sum += 1.0f - 1.0f / (1.0f + ahd);
                nvalid++;
            }
        }
        out[0] = nvalid ? (sum / (float)nvalid) : NAN;
    }
}

// ---------------------------------------------------------------------------
// Workspace layout (bytes):
//   [0,       256K)     bm     : 2 x 16 x 256 x 4 u64  (mask bitmaps)
//   [262144,  512K)     ebm    : 2 x 16 x 256 x 4 u64  (truncated edge bitmaps)
//   [524288,  1M)       gpts   : 16 x 4096 float2
//   [1048576, 1.5M)     ppts   : 16 x 4096 float2
//   [1572864, 5767168)  G16    : 32 maps x 256 x 256 u16 (vertical EDT)
//   [5767168, +64)      gcnt   : 16 int
//   [5767232, +64)      pcnt   : 16 int
//   [5767296, +8K)      partial: 2048 float
// ---------------------------------------------------------------------------
extern "C" void kernel_launch(void* const* d_in, const int* in_sizes, int n_in,
                              void* d_out, int out_size, void* d_ws, size_t ws_size,
                              hipStream_t stream) {
    const float* gth = (const float*)d_in[0];
    const float* pred = (const float*)d_in[1];
    float* out = (float*)d_out;
    char* ws = (char*)d_ws;

    u64* bm = (u64*)(ws);
    u64* ebm = (u64*)(ws + 262144);
    float2* gpts = (float2*)(ws + 524288);
    float2* ppts = (float2*)(ws + 1048576);
    u16* G16 = (u16*)(ws + 1572864);
    int* gcnt = (int*)(ws + 5767168);
    int* pcnt = (int*)(ws + 5767232);
    float* partial = (float*)(ws + 5767296);

    binarize_pack<<<8192, 256, 0, stream>>>(gth, pred, bm);
    edge_compact<<<32, 256, 0, stream>>>(bm, gpts, ppts, ebm, gcnt, pcnt);
    edt_vert<<<256, 256, 0, stream>>>(ebm, G16);
    nn_gather<<<NSLICE * 2 * NCH, 64, 0, stream>>>(gpts, ppts, gcnt, pcnt, G16, partial);
    finalize3<<<1, 512, 0, stream>>>(gcnt, pcnt, partial, out);
}